// Round 4
// baseline (219.748 us; speedup 1.0000x reference)
//
#include <hip/hip_runtime.h>
#include <hip/hip_fp16.h>

#define N_L 8
#define BP 4          // pairs per thread (fallback path)
#define BT 2          // triples per thread (fallback path)

#define NSEG 25
#define SEG_SHIFT 12  // 4096 rows per segment
#define SEG_ROWS 4096
#define NBINS (NSEG * NSEG)  // 625
#define EBUF_CAP 6656        // LDS sort buffer entries (8B each) = 53 KB
#define PROC_MAXT 2          // tri entries per thread in process (capT <= 1024)

// ---------------------------------------------------------------------------
// Block sum reduction (nw waves of 64); result valid on thread 0.
// ---------------------------------------------------------------------------
__device__ __forceinline__ float block_reduce_sum(float v, float* smem, int nw) {
#pragma unroll
  for (int off = 32; off > 0; off >>= 1) v += __shfl_down(v, off, 64);
  int lane = threadIdx.x & 63;
  int wid  = threadIdx.x >> 6;
  if (lane == 0) smem[wid] = v;
  __syncthreads();
  if ((int)threadIdx.x < nw) {
    v = smem[threadIdx.x];
    if (nw > 4) v += __shfl_down(v, 4, 64);
    if (nw > 2) v += __shfl_down(v, 2, 64);
    if (nw > 1) v += __shfl_down(v, 1, 64);
  }
  return v;
}

// ---------------------------------------------------------------------------
// Materialize fp16 softmax table: nV x 8 half = 16B rows. Softmax in f32,
// round-to-nearest fp16 at store. Also zero-inits acc + done-counter.
// Fast path: fidx == arange(nF); fallback binary search (LDS-staged).
// ---------------------------------------------------------------------------
__global__ __launch_bounds__(256) void materialize_P16(
    const float* __restrict__ tr, const float* __restrict__ fx,
    const int* __restrict__ fidx, int nF, int nV,
    int4* __restrict__ T, double* __restrict__ acc,
    unsigned int* __restrict__ cnt) {
  __shared__ int sf[1024];
  const bool ar = (nF == 0) || (fidx[0] == 0 && fidx[nF - 1] == nF - 1);
  const bool useLds = (!ar && nF <= 1024);
  if (useLds) {
    for (int j = threadIdx.x; j < nF; j += 256) sf[j] = fidx[j];
    __syncthreads();
  }
  int v = blockIdx.x * 256 + threadIdx.x;
  if (v == 0) { acc[0] = 0.0; cnt[0] = 0u; }
  if (v >= nV) return;

  const float* src;
  if (ar) {
    src = (v < nF) ? (fx + (size_t)v * N_L) : (tr + (size_t)(v - nF) * N_L);
  } else {
    const int* __restrict__ tab = useLds ? sf : fidx;
    int lo = 0, hi = nF;
    while (lo < hi) {
      int mid = (lo + hi) >> 1;
      if (tab[mid] < v) lo = mid + 1; else hi = mid;
    }
    src = (lo < nF && tab[lo] == v) ? (fx + (size_t)lo * N_L)
                                    : (tr + (size_t)(v - lo) * N_L);
  }
  float p[N_L];
  float4 a = *(const float4*)src;
  float4 b = *(const float4*)(src + 4);
  p[0] = a.x; p[1] = a.y; p[2] = a.z; p[3] = a.w;
  p[4] = b.x; p[5] = b.y; p[6] = b.z; p[7] = b.w;
  float m = p[0];
#pragma unroll
  for (int i = 1; i < N_L; ++i) m = fmaxf(m, p[i]);
  float s = 0.f;
#pragma unroll
  for (int i = 0; i < N_L; ++i) { p[i] = __expf(p[i] - m); s += p[i]; }
  float r = 1.0f / s;
  __half2 h0 = __floats2half2_rn(p[0] * r, p[1] * r);
  __half2 h1 = __floats2half2_rn(p[2] * r, p[3] * r);
  __half2 h2 = __floats2half2_rn(p[4] * r, p[5] * r);
  __half2 h3 = __floats2half2_rn(p[6] * r, p[7] * r);
  int4 o;
  o.x = *(const int*)&h0;
  o.y = *(const int*)&h1;
  o.z = *(const int*)&h2;
  o.w = *(const int*)&h3;
  T[v] = o;
}

__device__ __forceinline__ void unpack8(int4 q, float p[N_L]) {
  float2 f;
  f = __half22float2(*(const __half2*)&q.x); p[0] = f.x; p[1] = f.y;
  f = __half22float2(*(const __half2*)&q.y); p[2] = f.x; p[3] = f.y;
  f = __half22float2(*(const __half2*)&q.z); p[4] = f.x; p[5] = f.y;
  f = __half22float2(*(const __half2*)&q.w); p[6] = f.x; p[7] = f.y;
}

// ---------------------------------------------------------------------------
// Bin v2: per-block LDS counting sort, then COALESCED per-bin flush.
// R3's scatter wrote 2.8M entries to ~2.8M distinct lines (MSHR-bound);
// here each block writes each bin's run as a contiguous lane-coalesced
// burst -> ~5x fewer write line-touches.
// Three phases reusing one LDS buffer: pairs (coef -1), triple-edges
// (coef -4, bit31 flag), triples (t3 term, int4).
// ---------------------------------------------------------------------------
__device__ __forceinline__ void scan_reserve(
    unsigned* cntL, unsigned* baseL, unsigned* baseG, unsigned* wsum,
    unsigned int* __restrict__ curG, int tid) {
  // global range reservation per bin (order across blocks irrelevant)
  for (int b = tid; b < NBINS; b += 256)
    baseG[b] = cntL[b] ? atomicAdd(&curG[b], cntL[b]) : 0u;
  // exclusive scan of cntL into baseL: 3 bins/thread serial + block scan
  unsigned run = 0;
  int b0 = tid * 3;
#pragma unroll
  for (int k = 0; k < 3; ++k) {
    int b = b0 + k;
    if (b < NBINS) { baseL[b] = run; run += cntL[b]; }
  }
  wsum[tid] = run;
  __syncthreads();
  for (int off = 1; off < 256; off <<= 1) {
    unsigned x = 0;
    if (tid >= off) x = wsum[tid - off];
    __syncthreads();
    wsum[tid] += x;
    __syncthreads();
  }
  unsigned excl = (tid == 0) ? 0u : wsum[tid - 1];
#pragma unroll
  for (int k = 0; k < 3; ++k) {
    int b = b0 + k;
    if (b < NBINS) baseL[b] += excl;
  }
  // reset counters -> scatter cursors (all reads of cntL happened pre-scan)
  for (int b = tid; b < NBINS; b += 256) cntL[b] = 0u;
  __syncthreads();
}

__global__ __launch_bounds__(256) void bin_sort(
    const int* __restrict__ s1, int nP,
    const int* __restrict__ s2, int nT,
    unsigned int* __restrict__ curE, unsigned int* __restrict__ curT,
    unsigned long long* __restrict__ edgeBuf, int4* __restrict__ triBuf,
    int capE, int capT, int pChunk, int tChunk) {
  __shared__ unsigned long long bufE[EBUF_CAP];  // 53 KB (aliased as int4)
  __shared__ unsigned cntL[NBINS], baseL[NBINS], baseG[NBINS];
  __shared__ unsigned wsum[256];
  int4* bufT = (int4*)bufE;  // capacity EBUF_CAP/2

  const int tid  = threadIdx.x;
  const int wid  = tid >> 6;
  const int lane = tid & 63;
  const int p0 = blockIdx.x * pChunk, p1 = min(nP, p0 + pChunk);
  const int t0 = blockIdx.x * tChunk, t1 = min(nT, t0 + tChunk);
  const uint2* __restrict__ s1v = (const uint2*)s1;

  // ================= phase 0: pairs =================
  for (int b = tid; b < NBINS; b += 256) cntL[b] = 0u;
  __syncthreads();
  for (int i = p0 + tid; i < p1; i += 256) {
    uint2 e = s1v[i];
    atomicAdd(&cntL[(int)(e.x >> SEG_SHIFT) * NSEG + (int)(e.y >> SEG_SHIFT)], 1u);
  }
  __syncthreads();
  scan_reserve(cntL, baseL, baseG, wsum, curE, tid);
  for (int i = p0 + tid; i < p1; i += 256) {
    uint2 e = s1v[i];
    int b = (int)(e.x >> SEG_SHIFT) * NSEG + (int)(e.y >> SEG_SHIFT);
    unsigned slot = baseL[b] + atomicAdd(&cntL[b], 1u);
    bufE[slot] = ((unsigned long long)e.y << 32) | (unsigned long long)e.x;
  }
  __syncthreads();
  for (int b = wid; b < NBINS; b += 4) {
    unsigned n = cntL[b], lb = baseL[b], gb = baseG[b];
    for (unsigned k = lane; k < n; k += 64) {
      unsigned g = gb + k;
      if (g < (unsigned)capE) edgeBuf[(size_t)b * capE + g] = bufE[lb + k];
    }
  }
  __syncthreads();

  // ================= phase 1: triple edges (flagged, coef -4) ===========
  for (int b = tid; b < NBINS; b += 256) cntL[b] = 0u;
  __syncthreads();
  for (int i = t0 + tid; i < t1; i += 256) {
    int a = s2[3 * i], b = s2[3 * i + 1], c = s2[3 * i + 2];
    int sa = a >> SEG_SHIFT, sb = b >> SEG_SHIFT, sc = c >> SEG_SHIFT;
    atomicAdd(&cntL[sa * NSEG + sb], 1u);
    atomicAdd(&cntL[sa * NSEG + sc], 1u);
    atomicAdd(&cntL[sb * NSEG + sc], 1u);
  }
  __syncthreads();
  scan_reserve(cntL, baseL, baseG, wsum, curE, tid);
  for (int i = t0 + tid; i < t1; i += 256) {
    unsigned a = (unsigned)s2[3 * i], b = (unsigned)s2[3 * i + 1], c = (unsigned)s2[3 * i + 2];
    int sa = (int)(a >> SEG_SHIFT), sb = (int)(b >> SEG_SHIFT), sc = (int)(c >> SEG_SHIFT);
    int bb; unsigned slot;
    bb = sa * NSEG + sb;
    slot = baseL[bb] + atomicAdd(&cntL[bb], 1u);
    bufE[slot] = ((unsigned long long)b << 32) | (unsigned long long)(a | 0x80000000u);
    bb = sa * NSEG + sc;
    slot = baseL[bb] + atomicAdd(&cntL[bb], 1u);
    bufE[slot] = ((unsigned long long)c << 32) | (unsigned long long)(a | 0x80000000u);
    bb = sb * NSEG + sc;
    slot = baseL[bb] + atomicAdd(&cntL[bb], 1u);
    bufE[slot] = ((unsigned long long)c << 32) | (unsigned long long)(b | 0x80000000u);
  }
  __syncthreads();
  for (int b = wid; b < NBINS; b += 4) {
    unsigned n = cntL[b], lb = baseL[b], gb = baseG[b];
    for (unsigned k = lane; k < n; k += 64) {
      unsigned g = gb + k;
      if (g < (unsigned)capE) edgeBuf[(size_t)b * capE + g] = bufE[lb + k];
    }
  }
  __syncthreads();

  // ================= phase 2: triples (t3 term) =================
  for (int b = tid; b < NBINS; b += 256) cntL[b] = 0u;
  __syncthreads();
  for (int i = t0 + tid; i < t1; i += 256) {
    int a = s2[3 * i], b = s2[3 * i + 1];
    atomicAdd(&cntL[(a >> SEG_SHIFT) * NSEG + (b >> SEG_SHIFT)], 1u);
  }
  __syncthreads();
  scan_reserve(cntL, baseL, baseG, wsum, curT, tid);
  for (int i = t0 + tid; i < t1; i += 256) {
    int a = s2[3 * i], b = s2[3 * i + 1], c = s2[3 * i + 2];
    int bb = (a >> SEG_SHIFT) * NSEG + (b >> SEG_SHIFT);
    unsigned slot = baseL[bb] + atomicAdd(&cntL[bb], 1u);
    bufT[slot] = make_int4(a, b, c, 0);
  }
  __syncthreads();
  for (int b = wid; b < NBINS; b += 4) {
    unsigned n = cntL[b], lb = baseL[b], gb = baseG[b];
    for (unsigned k = lane; k < n; k += 64) {
      unsigned g = gb + k;
      if (g < (unsigned)capT) triBuf[(size_t)b * capT + g] = bufT[lb + k];
    }
  }
}

// ---------------------------------------------------------------------------
// Process v2: one 512-thread block (8 waves, better latency hiding) per
// (segA,segB) bin. Stage both 4096-row segments in LDS, prefetch t3's
// c-rows early, serve dots from LDS. Finalize via done-counter.
// ---------------------------------------------------------------------------
__global__ __launch_bounds__(512) void process_bins(
    const int4* __restrict__ T, int nV,
    const unsigned int* __restrict__ curE, const unsigned int* __restrict__ curT,
    const uint2* __restrict__ edgeBuf, const int4* __restrict__ triBuf,
    int capE, int capT,
    double* __restrict__ acc, unsigned int* __restrict__ cnt,
    int totalBlocks, float* __restrict__ out, double cst) {
  __shared__ int4 AS[SEG_ROWS];   // 64 KB
  __shared__ int4 BS[SEG_ROWS];   // 64 KB
  __shared__ float smem[8];
  const int tid = threadIdx.x;
  const int bin = blockIdx.x;
  const int sa = bin / NSEG, sb = bin % NSEG;
  const int aBase = sa << SEG_SHIFT, bBase = sb << SEG_SHIFT;

  const int nE  = min((int)curE[bin], capE);
  const int nTb = min((int)curT[bin], capT);

  // Random c-gathers issued EARLY (overlap with LDS staging + edge loop).
  int4 qc[PROC_MAXT];
  int ta[PROC_MAXT], tb[PROC_MAXT];
  float tw[PROC_MAXT];
  if (nTb > 0) {
#pragma unroll
    for (int u = 0; u < PROC_MAXT; ++u) {
      int j  = tid + u * 512;
      int jj = min(j, nTb - 1);
      tw[u]  = (j < nTb) ? 1.0f : 0.0f;
      int4 t = triBuf[(size_t)bin * capT + jj];  // jj always a real entry
      ta[u] = t.x; tb[u] = t.y;
      qc[u] = T[max(min(t.z, nV - 1), 0)];
    }
  }

  for (int r = tid; r < SEG_ROWS; r += 512) {
    AS[r] = T[min(aBase + r, nV - 1)];
    BS[r] = T[min(bBase + r, nV - 1)];
  }
  __syncthreads();

  float local = 0.f;
  for (int j = tid; j < nE; j += 512) {
    uint2 e = edgeBuf[(size_t)bin * capE + j];
    float wgt = (e.x & 0x80000000u) ? 4.0f : 1.0f;
    int al = (int)(e.x & 0x7fffffffu) - aBase;
    int bl = (int)e.y - bBase;
    float pa[N_L], pb[N_L];
    unpack8(AS[al], pa);
    unpack8(BS[bl], pb);
    float d = 0.f;
#pragma unroll
    for (int t = 0; t < N_L; ++t) d += pa[t] * pb[t];
    local -= wgt * d;
  }

  if (nTb > 0) {
#pragma unroll
    for (int u = 0; u < PROC_MAXT; ++u) {
      int al = max(min(ta[u] - aBase, SEG_ROWS - 1), 0);
      int bl = max(min(tb[u] - bBase, SEG_ROWS - 1), 0);
      float pa[N_L], pb[N_L], pc[N_L];
      unpack8(AS[al], pa);
      unpack8(BS[bl], pb);
      unpack8(qc[u], pc);
      float t3 = 0.f;
#pragma unroll
      for (int t = 0; t < N_L; ++t) t3 += pa[t] * pb[t] * pc[t];
      local += tw[u] * (16.0f / 3.0f) * t3;
    }
  }

  float bsum = block_reduce_sum(local, smem, 8);
  if (tid == 0) {
    atomicAdd(acc, (double)bsum);
    __threadfence();
    unsigned int done = atomicAdd(cnt, 1u);
    if (done == (unsigned int)(totalBlocks - 1)) {
      double total = atomicAdd(acc, 0.0);  // coherent read
      out[0] = (float)(cst + total);
    }
  }
}

// ---------------------------------------------------------------------------
// Fallback 1 (proven R2): random-gather over the fp16 table.
// ---------------------------------------------------------------------------
__global__ __launch_bounds__(256) void gather_energy16(
    const int4* __restrict__ T,
    const int* __restrict__ s1, int nP,
    const int* __restrict__ s2, int nT,
    double* __restrict__ acc, unsigned int* __restrict__ cnt,
    int pairBlocks, int totalBlocks,
    float* __restrict__ out, double cst) {
  __shared__ float smem[4];
  float local = 0.f;

  if ((int)blockIdx.x < pairBlocks) {
    const unsigned long long* __restrict__ s1q = (const unsigned long long*)s1;
    int base = blockIdx.x * (256 * BP) + threadIdx.x;
    int   va[BP], vb[BP];
    float w[BP];
#pragma unroll
    for (int u = 0; u < BP; ++u) {
      int i  = base + u * 256;
      int ii = min(i, nP - 1);
      w[u]   = (i < nP) ? 1.0f : 0.0f;
      unsigned long long q = __builtin_nontemporal_load(s1q + ii);
      va[u] = (int)(unsigned int)q;
      vb[u] = (int)(q >> 32);
    }
    int4 qa[BP], qb[BP];
#pragma unroll
    for (int u = 0; u < BP; ++u) { qa[u] = T[va[u]]; qb[u] = T[vb[u]]; }
#pragma unroll
    for (int u = 0; u < BP; ++u) {
      float pa[N_L], pb[N_L];
      unpack8(qa[u], pa);
      unpack8(qb[u], pb);
      float d = 0.f;
#pragma unroll
      for (int t = 0; t < N_L; ++t) d += pa[t] * pb[t];
      local -= w[u] * d;
    }
  } else {
    int base = (blockIdx.x - pairBlocks) * (256 * BT) + threadIdx.x;
    int   v0[BT], v1[BT], v2[BT];
    float w[BT];
#pragma unroll
    for (int u = 0; u < BT; ++u) {
      int i  = base + u * 256;
      int ii = min(i, nT - 1);
      w[u]   = (i < nT) ? 1.0f : 0.0f;
      v0[u] = __builtin_nontemporal_load(s2 + 3 * ii + 0);
      v1[u] = __builtin_nontemporal_load(s2 + 3 * ii + 1);
      v2[u] = __builtin_nontemporal_load(s2 + 3 * ii + 2);
    }
    int4 qa[BT], qb[BT], qc[BT];
#pragma unroll
    for (int u = 0; u < BT; ++u) { qa[u] = T[v0[u]]; qb[u] = T[v1[u]]; qc[u] = T[v2[u]]; }
#pragma unroll
    for (int u = 0; u < BT; ++u) {
      float pa[N_L], pb[N_L], pc[N_L];
      unpack8(qa[u], pa);
      unpack8(qb[u], pb);
      unpack8(qc[u], pc);
      float d01 = 0.f, d02 = 0.f, d12 = 0.f, t3 = 0.f;
#pragma unroll
      for (int t = 0; t < N_L; ++t) {
        d01 += pa[t] * pb[t];
        d02 += pa[t] * pc[t];
        d12 += pb[t] * pc[t];
        t3  += pa[t] * pb[t] * pc[t];
      }
      local += w[u] * (-4.0f * (d01 + d02 + d12) + (16.0f / 3.0f) * t3);
    }
  }

  float bsum = block_reduce_sum(local, smem, 4);
  if (threadIdx.x == 0) {
    atomicAdd(acc, (double)bsum);
    __threadfence();
    unsigned int done = atomicAdd(cnt, 1u);
    if (done == (unsigned int)(totalBlocks - 1)) {
      double total = atomicAdd(acc, 0.0);
      out[0] = (float)(cst + total);
    }
  }
}

// ---------------------------------------------------------------------------
// Fallback 2 (proven R1): fully fused f32 kernel, no workspace table.
// ---------------------------------------------------------------------------
__device__ __forceinline__ const float* row_ptr(
    int v, bool ar, const int* __restrict__ tab, int nF,
    const float* __restrict__ tr, const float* __restrict__ fx) {
  if (ar) {
    return (v < nF) ? (fx + (size_t)v * N_L) : (tr + (size_t)(v - nF) * N_L);
  }
  int lo = 0, hi = nF;
  while (lo < hi) {
    int mid = (lo + hi) >> 1;
    if (tab[mid] < v) lo = mid + 1; else hi = mid;
  }
  return (lo < nF && tab[lo] == v) ? (fx + (size_t)lo * N_L)
                                   : (tr + (size_t)(v - lo) * N_L);
}

__device__ __forceinline__ void softmax8(float p[N_L]) {
  float m = p[0];
#pragma unroll
  for (int i = 1; i < N_L; ++i) m = fmaxf(m, p[i]);
  float s = 0.f;
#pragma unroll
  for (int i = 0; i < N_L; ++i) { p[i] = __expf(p[i] - m); s += p[i]; }
  float r = 1.0f / s;
#pragma unroll
  for (int i = 0; i < N_L; ++i) p[i] *= r;
}

__global__ __launch_bounds__(256) void fused_energy(
    const float* __restrict__ tr, const float* __restrict__ fx,
    const int* __restrict__ fidx, int nF,
    const int* __restrict__ s1, int nP,
    const int* __restrict__ s2, int nT,
    double* __restrict__ acc, unsigned int* __restrict__ cnt,
    int pairBlocks, int totalBlocks,
    float* __restrict__ out, double cst) {
  __shared__ float smem[4];
  __shared__ int sf[1024];

  const bool ar = (nF == 0) || (fidx[0] == 0 && fidx[nF - 1] == nF - 1);
  const bool useLds = (!ar && nF <= 1024);
  if (useLds) {
    for (int j = threadIdx.x; j < nF; j += 256) sf[j] = fidx[j];
    __syncthreads();
  }
  const int* __restrict__ tab = useLds ? sf : fidx;

  float local = 0.f;

  if ((int)blockIdx.x < pairBlocks) {
    const unsigned long long* __restrict__ s1q = (const unsigned long long*)s1;
    int base = blockIdx.x * (256 * BP) + threadIdx.x;
    int   va[BP], vb[BP];
    float w[BP];
#pragma unroll
    for (int u = 0; u < BP; ++u) {
      int i  = base + u * 256;
      int ii = min(i, nP - 1);
      w[u]   = (i < nP) ? 1.0f : 0.0f;
      unsigned long long q = __builtin_nontemporal_load(s1q + ii);
      va[u] = (int)(unsigned int)q;
      vb[u] = (int)(q >> 32);
    }
    float4 a0[BP], a1[BP], b0[BP], b1[BP];
#pragma unroll
    for (int u = 0; u < BP; ++u) {
      const float4* A = (const float4*)row_ptr(va[u], ar, tab, nF, tr, fx);
      const float4* B = (const float4*)row_ptr(vb[u], ar, tab, nF, tr, fx);
      a0[u] = A[0]; a1[u] = A[1];
      b0[u] = B[0]; b1[u] = B[1];
    }
#pragma unroll
    for (int u = 0; u < BP; ++u) {
      float pa[8] = {a0[u].x, a0[u].y, a0[u].z, a0[u].w, a1[u].x, a1[u].y, a1[u].z, a1[u].w};
      float pb[8] = {b0[u].x, b0[u].y, b0[u].z, b0[u].w, b1[u].x, b1[u].y, b1[u].z, b1[u].w};
      softmax8(pa);
      softmax8(pb);
      float d = 0.f;
#pragma unroll
      for (int t = 0; t < N_L; ++t) d += pa[t] * pb[t];
      local -= w[u] * d;
    }
  } else {
    int base = (blockIdx.x - pairBlocks) * (256 * BT) + threadIdx.x;
    int   v0[BT], v1[BT], v2[BT];
    float w[BT];
#pragma unroll
    for (int u = 0; u < BT; ++u) {
      int i  = base + u * 256;
      int ii = min(i, nT - 1);
      w[u]   = (i < nT) ? 1.0f : 0.0f;
      v0[u] = __builtin_nontemporal_load(s2 + 3 * ii + 0);
      v1[u] = __builtin_nontemporal_load(s2 + 3 * ii + 1);
      v2[u] = __builtin_nontemporal_load(s2 + 3 * ii + 2);
    }
    float4 a0[BT], a1[BT], b0[BT], b1[BT], c0[BT], c1[BT];
#pragma unroll
    for (int u = 0; u < BT; ++u) {
      const float4* A = (const float4*)row_ptr(v0[u], ar, tab, nF, tr, fx);
      const float4* B = (const float4*)row_ptr(v1[u], ar, tab, nF, tr, fx);
      const float4* C = (const float4*)row_ptr(v2[u], ar, tab, nF, tr, fx);
      a0[u] = A[0]; a1[u] = A[1];
      b0[u] = B[0]; b1[u] = B[1];
      c0[u] = C[0]; c1[u] = C[1];
    }
#pragma unroll
    for (int u = 0; u < BT; ++u) {
      float pa[8] = {a0[u].x, a0[u].y, a0[u].z, a0[u].w, a1[u].x, a1[u].y, a1[u].z, a1[u].w};
      float pb[8] = {b0[u].x, b0[u].y, b0[u].z, b0[u].w, b1[u].x, b1[u].y, b1[u].z, b1[u].w};
      float pc[8] = {c0[u].x, c0[u].y, c0[u].z, c0[u].w, c1[u].x, c1[u].y, c1[u].z, c1[u].w};
      softmax8(pa);
      softmax8(pb);
      softmax8(pc);
      float d01 = 0.f, d02 = 0.f, d12 = 0.f, t3 = 0.f;
#pragma unroll
      for (int t = 0; t < N_L; ++t) {
        d01 += pa[t] * pb[t];
        d02 += pa[t] * pc[t];
        d12 += pb[t] * pc[t];
        t3  += pa[t] * pb[t] * pc[t];
      }
      local += w[u] * (-4.0f * (d01 + d02 + d12) + (16.0f / 3.0f) * t3);
    }
  }

  float bsum = block_reduce_sum(local, smem, 4);
  if (threadIdx.x == 0) {
    atomicAdd(acc, (double)bsum);
    __threadfence();
    unsigned int done = atomicAdd(cnt, 1u);
    if (done == (unsigned int)(totalBlocks - 1)) {
      double total = atomicAdd(acc, 0.0);
      out[0] = (float)(cst + total);
    }
  }
}

extern "C" void kernel_launch(void* const* d_in, const int* in_sizes, int n_in,
                              void* d_out, int out_size, void* d_ws, size_t ws_size,
                              hipStream_t stream) {
  const float* tr   = (const float*)d_in[0];  // (N_V-N_FIXED, 8) f32
  const float* fx   = (const float*)d_in[1];  // (N_FIXED, 8) f32
  const int*   fidx = (const int*)d_in[2];    // (N_FIXED,) i32 (sorted)
  const int*   s1   = (const int*)d_in[3];    // (nP, 2) i32
  const int*   s2   = (const int*)d_in[4];    // (nT, 3) i32

  int nF = in_sizes[2];
  int nP = in_sizes[3] / 2;
  int nT = in_sizes[4] / 3;
  int nV = (in_sizes[0] + in_sizes[1]) / N_L;

  float* out = (float*)d_out;
  double cst = 2.0 * (double)nP + 8.0 * (double)nT;

  // Binned-path capacities (runtime-sized, 32-aligned, ~1.3x mean).
  int meanE = (nP + 3 * nT) / NBINS + 1;
  int capE  = ((meanE + meanE / 4 + 128) + 31) & ~31;
  int meanT = nT / NBINS + 1;
  int capT  = ((meanT + meanT / 4 + 64) + 31) & ~31;

  // bin_sort grid: chunks must fit the LDS sort buffer.
  int nblk = 192;
  for (;;) {
    int pc = (nP + nblk - 1) / nblk;
    int tc = (nT + nblk - 1) / nblk;
    if (pc <= EBUF_CAP && 3 * tc <= EBUF_CAP && tc <= EBUF_CAP / 2) break;
    nblk += 64;
  }
  int pChunk = (nP + nblk - 1) / nblk;
  int tChunk = (nT + nblk - 1) / nblk;

  // Binned-path workspace layout.
  // [0,8)=acc  [16,20)=cnt  [1024,..)=curE[625]  [4096,..)=curT[625]
  // [8192,..)=T (nV*16B)  then edgeBuf, then triBuf.
  size_t offT    = 8192;
  size_t offEdge = offT + (size_t)nV * 16;
  size_t offTri  = offEdge + (size_t)NBINS * capE * 8;
  size_t needBin = offTri + (size_t)NBINS * capT * 16;

  if (ws_size >= needBin && capT <= 512 * PROC_MAXT && nV <= NSEG * SEG_ROWS) {
    double*             acc  = (double*)d_ws;
    unsigned int*       cnt  = (unsigned int*)((char*)d_ws + 16);
    unsigned int*       curE = (unsigned int*)((char*)d_ws + 1024);
    unsigned int*       curT = (unsigned int*)((char*)d_ws + 4096);
    int4*               T    = (int4*)((char*)d_ws + offT);
    unsigned long long* eBuf = (unsigned long long*)((char*)d_ws + offEdge);
    int4*               tBuf = (int4*)((char*)d_ws + offTri);

    hipMemsetAsync(d_ws, 0, 8192, stream);  // acc, cnt, cursors
    materialize_P16<<<(nV + 255) / 256, 256, 0, stream>>>(tr, fx, fidx, nF, nV, T, acc, cnt);
    bin_sort<<<nblk, 256, 0, stream>>>(s1, nP, s2, nT, curE, curT, eBuf, tBuf,
                                       capE, capT, pChunk, tChunk);
    process_bins<<<NBINS, 512, 0, stream>>>(T, nV, curE, curT, (const uint2*)eBuf, tBuf,
                                            capE, capT, acc, cnt, NBINS, out, cst);
    return;
  }

  // Fallbacks: proven R2 gather path, then R1 fused path.
  double*       acc = (double*)d_ws;
  unsigned int* cnt = (unsigned int*)((char*)d_ws + 16);
  int4*         T   = (int4*)((char*)d_ws + 256);

  int pairBlocks  = (nP + 256 * BP - 1) / (256 * BP);
  int triBlocks   = (nT + 256 * BT - 1) / (256 * BT);
  int totalBlocks = pairBlocks + triBlocks;

  size_t need16 = 256 + (size_t)nV * 16;
  if (ws_size >= need16) {
    materialize_P16<<<(nV + 255) / 256, 256, 0, stream>>>(tr, fx, fidx, nF, nV, T, acc, cnt);
    gather_energy16<<<totalBlocks, 256, 0, stream>>>(
        T, s1, nP, s2, nT, acc, cnt, pairBlocks, totalBlocks, out, cst);
  } else {
    hipMemsetAsync(d_ws, 0, 32, stream);
    fused_energy<<<totalBlocks, 256, 0, stream>>>(
        tr, fx, fidx, nF, s1, nP, s2, nT, acc, cnt,
        pairBlocks, totalBlocks, out, cst);
  }
}

// Round 5
// 106.505 us; speedup vs baseline: 2.0633x; 2.0633x over previous
//
#include <hip/hip_runtime.h>
#include <hip/hip_fp16.h>

#define N_L 8
#define BP 8   // pairs per thread  (R4 probe: 4->8, test MSHR saturation)
#define BT 4   // triples per thread (R4 probe: 2->4)

// ---------------------------------------------------------------------------
// Block (256 threads = 4 waves) sum reduction; result valid on thread 0.
// ---------------------------------------------------------------------------
__device__ __forceinline__ float block_reduce_sum(float v, float* smem) {
#pragma unroll
  for (int off = 32; off > 0; off >>= 1) v += __shfl_down(v, off, 64);
  int lane = threadIdx.x & 63;
  int wid  = threadIdx.x >> 6;
  if (lane == 0) smem[wid] = v;
  __syncthreads();
  if (threadIdx.x < 4) {
    v = smem[threadIdx.x];
    v += __shfl_down(v, 2, 64);
    v += __shfl_down(v, 1, 64);
  }
  return v;
}

// ---------------------------------------------------------------------------
// Materialize fp16 softmax table: nV x 8 half = 16B rows (one dwordx4 per
// random row-gather). Softmax in f32, round-to-nearest fp16 at store.
// Also zero-inits acc + done-counter.
// Fast path: fidx == arange(nF); fallback binary search (LDS-staged).
// ---------------------------------------------------------------------------
__global__ __launch_bounds__(256) void materialize_P16(
    const float* __restrict__ tr, const float* __restrict__ fx,
    const int* __restrict__ fidx, int nF, int nV,
    int4* __restrict__ T, double* __restrict__ acc,
    unsigned int* __restrict__ cnt) {
  __shared__ int sf[1024];
  const bool ar = (nF == 0) || (fidx[0] == 0 && fidx[nF - 1] == nF - 1);
  const bool useLds = (!ar && nF <= 1024);
  if (useLds) {
    for (int j = threadIdx.x; j < nF; j += 256) sf[j] = fidx[j];
    __syncthreads();
  }
  int v = blockIdx.x * 256 + threadIdx.x;
  if (v == 0) { acc[0] = 0.0; cnt[0] = 0u; }
  if (v >= nV) return;

  const float* src;
  if (ar) {
    src = (v < nF) ? (fx + (size_t)v * N_L) : (tr + (size_t)(v - nF) * N_L);
  } else {
    const int* __restrict__ tab = useLds ? sf : fidx;
    int lo = 0, hi = nF;
    while (lo < hi) {
      int mid = (lo + hi) >> 1;
      if (tab[mid] < v) lo = mid + 1; else hi = mid;
    }
    src = (lo < nF && tab[lo] == v) ? (fx + (size_t)lo * N_L)
                                    : (tr + (size_t)(v - lo) * N_L);
  }
  float p[N_L];
  float4 a = *(const float4*)src;
  float4 b = *(const float4*)(src + 4);
  p[0] = a.x; p[1] = a.y; p[2] = a.z; p[3] = a.w;
  p[4] = b.x; p[5] = b.y; p[6] = b.z; p[7] = b.w;
  float m = p[0];
#pragma unroll
  for (int i = 1; i < N_L; ++i) m = fmaxf(m, p[i]);
  float s = 0.f;
#pragma unroll
  for (int i = 0; i < N_L; ++i) { p[i] = __expf(p[i] - m); s += p[i]; }
  float r = 1.0f / s;
  __half2 h0 = __floats2half2_rn(p[0] * r, p[1] * r);
  __half2 h1 = __floats2half2_rn(p[2] * r, p[3] * r);
  __half2 h2 = __floats2half2_rn(p[4] * r, p[5] * r);
  __half2 h3 = __floats2half2_rn(p[6] * r, p[7] * r);
  int4 o;
  o.x = *(const int*)&h0;
  o.y = *(const int*)&h1;
  o.z = *(const int*)&h2;
  o.w = *(const int*)&h3;
  T[v] = o;
}

__device__ __forceinline__ void unpack8(int4 q, float p[N_L]) {
  float2 f;
  f = __half22float2(*(const __half2*)&q.x); p[0] = f.x; p[1] = f.y;
  f = __half22float2(*(const __half2*)&q.y); p[2] = f.x; p[3] = f.y;
  f = __half22float2(*(const __half2*)&q.z); p[4] = f.x; p[5] = f.y;
  f = __half22float2(*(const __half2*)&q.w); p[6] = f.x; p[7] = f.y;
}

// ---------------------------------------------------------------------------
// Gather over the 16B-row fp16 table (proven R2 structure). All index loads
// issue first (non-temporal), then ALL row loads (independent, one waitcnt
// group), then compute. Tails branch-free. Finalize fused via done-counter.
// ---------------------------------------------------------------------------
__global__ __launch_bounds__(256) void gather_energy16(
    const int4* __restrict__ T,
    const int* __restrict__ s1, int nP,
    const int* __restrict__ s2, int nT,
    double* __restrict__ acc, unsigned int* __restrict__ cnt,
    int pairBlocks, int totalBlocks,
    float* __restrict__ out, double cst) {
  __shared__ float smem[4];
  float local = 0.f;

  if ((int)blockIdx.x < pairBlocks) {
    const unsigned long long* __restrict__ s1q = (const unsigned long long*)s1;
    int base = blockIdx.x * (256 * BP) + threadIdx.x;
    int   va[BP], vb[BP];
    float w[BP];
#pragma unroll
    for (int u = 0; u < BP; ++u) {
      int i  = base + u * 256;
      int ii = min(i, nP - 1);
      w[u]   = (i < nP) ? 1.0f : 0.0f;
      unsigned long long q = __builtin_nontemporal_load(s1q + ii);
      va[u] = (int)(unsigned int)q;
      vb[u] = (int)(q >> 32);
    }
    int4 qa[BP], qb[BP];
#pragma unroll
    for (int u = 0; u < BP; ++u) { qa[u] = T[va[u]]; qb[u] = T[vb[u]]; }
#pragma unroll
    for (int u = 0; u < BP; ++u) {
      float pa[N_L], pb[N_L];
      unpack8(qa[u], pa);
      unpack8(qb[u], pb);
      float d = 0.f;
#pragma unroll
      for (int t = 0; t < N_L; ++t) d += pa[t] * pb[t];
      local -= w[u] * d;
    }
  } else {
    int base = (blockIdx.x - pairBlocks) * (256 * BT) + threadIdx.x;
    int   v0[BT], v1[BT], v2[BT];
    float w[BT];
#pragma unroll
    for (int u = 0; u < BT; ++u) {
      int i  = base + u * 256;
      int ii = min(i, nT - 1);
      w[u]   = (i < nT) ? 1.0f : 0.0f;
      v0[u] = __builtin_nontemporal_load(s2 + 3 * ii + 0);
      v1[u] = __builtin_nontemporal_load(s2 + 3 * ii + 1);
      v2[u] = __builtin_nontemporal_load(s2 + 3 * ii + 2);
    }
    int4 qa[BT], qb[BT], qc[BT];
#pragma unroll
    for (int u = 0; u < BT; ++u) { qa[u] = T[v0[u]]; qb[u] = T[v1[u]]; qc[u] = T[v2[u]]; }
#pragma unroll
    for (int u = 0; u < BT; ++u) {
      float pa[N_L], pb[N_L], pc[N_L];
      unpack8(qa[u], pa);
      unpack8(qb[u], pb);
      unpack8(qc[u], pc);
      float d01 = 0.f, d02 = 0.f, d12 = 0.f, t3 = 0.f;
#pragma unroll
      for (int t = 0; t < N_L; ++t) {
        d01 += pa[t] * pb[t];
        d02 += pa[t] * pc[t];
        d12 += pb[t] * pc[t];
        t3  += pa[t] * pb[t] * pc[t];
      }
      local += w[u] * (-4.0f * (d01 + d02 + d12) + (16.0f / 3.0f) * t3);
    }
  }

  float bsum = block_reduce_sum(local, smem);
  if (threadIdx.x == 0) {
    atomicAdd(acc, (double)bsum);
    __threadfence();
    unsigned int done = atomicAdd(cnt, 1u);
    if (done == (unsigned int)(totalBlocks - 1)) {
      double total = atomicAdd(acc, 0.0);  // coherent read
      out[0] = (float)(cst + total);
    }
  }
}

// ---------------------------------------------------------------------------
// ws-too-small fallback: fully fused f32 kernel (proven R1), no table.
// ---------------------------------------------------------------------------
__device__ __forceinline__ const float* row_ptr(
    int v, bool ar, const int* __restrict__ tab, int nF,
    const float* __restrict__ tr, const float* __restrict__ fx) {
  if (ar) {
    return (v < nF) ? (fx + (size_t)v * N_L) : (tr + (size_t)(v - nF) * N_L);
  }
  int lo = 0, hi = nF;
  while (lo < hi) {
    int mid = (lo + hi) >> 1;
    if (tab[mid] < v) lo = mid + 1; else hi = mid;
  }
  return (lo < nF && tab[lo] == v) ? (fx + (size_t)lo * N_L)
                                   : (tr + (size_t)(v - lo) * N_L);
}

__device__ __forceinline__ void softmax8(float p[N_L]) {
  float m = p[0];
#pragma unroll
  for (int i = 1; i < N_L; ++i) m = fmaxf(m, p[i]);
  float s = 0.f;
#pragma unroll
  for (int i = 0; i < N_L; ++i) { p[i] = __expf(p[i] - m); s += p[i]; }
  float r = 1.0f / s;
#pragma unroll
  for (int i = 0; i < N_L; ++i) p[i] *= r;
}

__global__ __launch_bounds__(256) void fused_energy(
    const float* __restrict__ tr, const float* __restrict__ fx,
    const int* __restrict__ fidx, int nF,
    const int* __restrict__ s1, int nP,
    const int* __restrict__ s2, int nT,
    double* __restrict__ acc, unsigned int* __restrict__ cnt,
    int pairBlocks, int totalBlocks,
    float* __restrict__ out, double cst) {
  __shared__ float smem[4];
  __shared__ int sf[1024];

  const bool ar = (nF == 0) || (fidx[0] == 0 && fidx[nF - 1] == nF - 1);
  const bool useLds = (!ar && nF <= 1024);
  if (useLds) {
    for (int j = threadIdx.x; j < nF; j += 256) sf[j] = fidx[j];
    __syncthreads();
  }
  const int* __restrict__ tab = useLds ? sf : fidx;

  float local = 0.f;

  if ((int)blockIdx.x < pairBlocks) {
    const unsigned long long* __restrict__ s1q = (const unsigned long long*)s1;
    int base = blockIdx.x * (256 * 4) + threadIdx.x;
    int   va[4], vb[4];
    float w[4];
#pragma unroll
    for (int u = 0; u < 4; ++u) {
      int i  = base + u * 256;
      int ii = min(i, nP - 1);
      w[u]   = (i < nP) ? 1.0f : 0.0f;
      unsigned long long q = __builtin_nontemporal_load(s1q + ii);
      va[u] = (int)(unsigned int)q;
      vb[u] = (int)(q >> 32);
    }
    float4 a0[4], a1[4], b0[4], b1[4];
#pragma unroll
    for (int u = 0; u < 4; ++u) {
      const float4* A = (const float4*)row_ptr(va[u], ar, tab, nF, tr, fx);
      const float4* B = (const float4*)row_ptr(vb[u], ar, tab, nF, tr, fx);
      a0[u] = A[0]; a1[u] = A[1];
      b0[u] = B[0]; b1[u] = B[1];
    }
#pragma unroll
    for (int u = 0; u < 4; ++u) {
      float pa[8] = {a0[u].x, a0[u].y, a0[u].z, a0[u].w, a1[u].x, a1[u].y, a1[u].z, a1[u].w};
      float pb[8] = {b0[u].x, b0[u].y, b0[u].z, b0[u].w, b1[u].x, b1[u].y, b1[u].z, b1[u].w};
      softmax8(pa);
      softmax8(pb);
      float d = 0.f;
#pragma unroll
      for (int t = 0; t < N_L; ++t) d += pa[t] * pb[t];
      local -= w[u] * d;
    }
  } else {
    int base = (blockIdx.x - pairBlocks) * (256 * 2) + threadIdx.x;
    int   v0[2], v1[2], v2[2];
    float w[2];
#pragma unroll
    for (int u = 0; u < 2; ++u) {
      int i  = base + u * 256;
      int ii = min(i, nT - 1);
      w[u]   = (i < nT) ? 1.0f : 0.0f;
      v0[u] = __builtin_nontemporal_load(s2 + 3 * ii + 0);
      v1[u] = __builtin_nontemporal_load(s2 + 3 * ii + 1);
      v2[u] = __builtin_nontemporal_load(s2 + 3 * ii + 2);
    }
    float4 a0[2], a1[2], b0[2], b1[2], c0[2], c1[2];
#pragma unroll
    for (int u = 0; u < 2; ++u) {
      const float4* A = (const float4*)row_ptr(v0[u], ar, tab, nF, tr, fx);
      const float4* B = (const float4*)row_ptr(v1[u], ar, tab, nF, tr, fx);
      const float4* C = (const float4*)row_ptr(v2[u], ar, tab, nF, tr, fx);
      a0[u] = A[0]; a1[u] = A[1];
      b0[u] = B[0]; b1[u] = B[1];
      c0[u] = C[0]; c1[u] = C[1];
    }
#pragma unroll
    for (int u = 0; u < 2; ++u) {
      float pa[8] = {a0[u].x, a0[u].y, a0[u].z, a0[u].w, a1[u].x, a1[u].y, a1[u].z, a1[u].w};
      float pb[8] = {b0[u].x, b0[u].y, b0[u].z, b0[u].w, b1[u].x, b1[u].y, b1[u].z, b1[u].w};
      float pc[8] = {c0[u].x, c0[u].y, c0[u].z, c0[u].w, c1[u].x, c1[u].y, c1[u].z, c1[u].w};
      softmax8(pa);
      softmax8(pb);
      softmax8(pc);
      float d01 = 0.f, d02 = 0.f, d12 = 0.f, t3 = 0.f;
#pragma unroll
      for (int t = 0; t < N_L; ++t) {
        d01 += pa[t] * pb[t];
        d02 += pa[t] * pc[t];
        d12 += pb[t] * pc[t];
        t3  += pa[t] * pb[t] * pc[t];
      }
      local += w[u] * (-4.0f * (d01 + d02 + d12) + (16.0f / 3.0f) * t3);
    }
  }

  float bsum = block_reduce_sum(local, smem);
  if (threadIdx.x == 0) {
    atomicAdd(acc, (double)bsum);
    __threadfence();
    unsigned int done = atomicAdd(cnt, 1u);
    if (done == (unsigned int)(totalBlocks - 1)) {
      double total = atomicAdd(acc, 0.0);
      out[0] = (float)(cst + total);
    }
  }
}

extern "C" void kernel_launch(void* const* d_in, const int* in_sizes, int n_in,
                              void* d_out, int out_size, void* d_ws, size_t ws_size,
                              hipStream_t stream) {
  const float* tr   = (const float*)d_in[0];  // (N_V-N_FIXED, 8) f32
  const float* fx   = (const float*)d_in[1];  // (N_FIXED, 8) f32
  const int*   fidx = (const int*)d_in[2];    // (N_FIXED,) i32 (sorted)
  const int*   s1   = (const int*)d_in[3];    // (nP, 2) i32
  const int*   s2   = (const int*)d_in[4];    // (nT, 3) i32

  int nF = in_sizes[2];
  int nP = in_sizes[3] / 2;
  int nT = in_sizes[4] / 3;
  int nV = (in_sizes[0] + in_sizes[1]) / N_L;

  double*       acc = (double*)d_ws;                      // @0, 8B
  unsigned int* cnt = (unsigned int*)((char*)d_ws + 16);  // @16, 4B
  int4*         T   = (int4*)((char*)d_ws + 256);         // nV x 16B fp16 rows
  float*        out = (float*)d_out;

  double cst = 2.0 * (double)nP + 8.0 * (double)nT;

  size_t need16 = 256 + (size_t)nV * 16;
  if (ws_size >= need16) {
    int pairBlocks  = (nP + 256 * BP - 1) / (256 * BP);
    int triBlocks   = (nT + 256 * BT - 1) / (256 * BT);
    int totalBlocks = pairBlocks + triBlocks;
    materialize_P16<<<(nV + 255) / 256, 256, 0, stream>>>(tr, fx, fidx, nF, nV, T, acc, cnt);
    gather_energy16<<<totalBlocks, 256, 0, stream>>>(
        T, s1, nP, s2, nT, acc, cnt, pairBlocks, totalBlocks, out, cst);
  } else {
    int pairBlocks  = (nP + 256 * 4 - 1) / (256 * 4);
    int triBlocks   = (nT + 256 * 2 - 1) / (256 * 2);
    int totalBlocks = pairBlocks + triBlocks;
    hipMemsetAsync(d_ws, 0, 32, stream);
    fused_energy<<<totalBlocks, 256, 0, stream>>>(
        tr, fx, fidx, nF, s1, nP, s2, nT, acc, cnt,
        pairBlocks, totalBlocks, out, cst);
  }
}

// Round 7
// 97.975 us; speedup vs baseline: 2.2429x; 1.0871x over previous
//
#include <hip/hip_runtime.h>
#include <hip/hip_fp16.h>

#define N_L 8
#define BP 16  // pairs per thread  (depth probe: 8->16)
#define BT 8   // triples per thread (depth probe: 4->8)

// ---------------------------------------------------------------------------
// Block (256 threads = 4 waves) sum reduction; result valid on thread 0.
// ---------------------------------------------------------------------------
__device__ __forceinline__ float block_reduce_sum(float v, float* smem) {
#pragma unroll
  for (int off = 32; off > 0; off >>= 1) v += __shfl_down(v, off, 64);
  int lane = threadIdx.x & 63;
  int wid  = threadIdx.x >> 6;
  if (lane == 0) smem[wid] = v;
  __syncthreads();
  if (threadIdx.x < 4) {
    v = smem[threadIdx.x];
    v += __shfl_down(v, 2, 64);
    v += __shfl_down(v, 1, 64);
  }
  return v;
}

// ---------------------------------------------------------------------------
// Materialize fp16 softmax table: nV x 8 half = 16B rows (one dwordx4 per
// random row-gather). Softmax in f32, round-to-nearest fp16 at store.
// Also zero-inits acc + done-counter.
// Fast path: fidx == arange(nF); fallback binary search (LDS-staged).
// ---------------------------------------------------------------------------
__global__ __launch_bounds__(256) void materialize_P16(
    const float* __restrict__ tr, const float* __restrict__ fx,
    const int* __restrict__ fidx, int nF, int nV,
    int4* __restrict__ T, double* __restrict__ acc,
    unsigned int* __restrict__ cnt) {
  __shared__ int sf[1024];
  const bool ar = (nF == 0) || (fidx[0] == 0 && fidx[nF - 1] == nF - 1);
  const bool useLds = (!ar && nF <= 1024);
  if (useLds) {
    for (int j = threadIdx.x; j < nF; j += 256) sf[j] = fidx[j];
    __syncthreads();
  }
  int v = blockIdx.x * 256 + threadIdx.x;
  if (v == 0) { acc[0] = 0.0; cnt[0] = 0u; }
  if (v >= nV) return;

  const float* src;
  if (ar) {
    src = (v < nF) ? (fx + (size_t)v * N_L) : (tr + (size_t)(v - nF) * N_L);
  } else {
    const int* __restrict__ tab = useLds ? sf : fidx;
    int lo = 0, hi = nF;
    while (lo < hi) {
      int mid = (lo + hi) >> 1;
      if (tab[mid] < v) lo = mid + 1; else hi = mid;
    }
    src = (lo < nF && tab[lo] == v) ? (fx + (size_t)lo * N_L)
                                    : (tr + (size_t)(v - lo) * N_L);
  }
  float p[N_L];
  float4 a = *(const float4*)src;
  float4 b = *(const float4*)(src + 4);
  p[0] = a.x; p[1] = a.y; p[2] = a.z; p[3] = a.w;
  p[4] = b.x; p[5] = b.y; p[6] = b.z; p[7] = b.w;
  float m = p[0];
#pragma unroll
  for (int i = 1; i < N_L; ++i) m = fmaxf(m, p[i]);
  float s = 0.f;
#pragma unroll
  for (int i = 0; i < N_L; ++i) { p[i] = __expf(p[i] - m); s += p[i]; }
  float r = 1.0f / s;
  __half2 h0 = __floats2half2_rn(p[0] * r, p[1] * r);
  __half2 h1 = __floats2half2_rn(p[2] * r, p[3] * r);
  __half2 h2 = __floats2half2_rn(p[4] * r, p[5] * r);
  __half2 h3 = __floats2half2_rn(p[6] * r, p[7] * r);
  int4 o;
  o.x = *(const int*)&h0;
  o.y = *(const int*)&h1;
  o.z = *(const int*)&h2;
  o.w = *(const int*)&h3;
  T[v] = o;
}

__device__ __forceinline__ void unpack8(int4 q, float p[N_L]) {
  float2 f;
  f = __half22float2(*(const __half2*)&q.x); p[0] = f.x; p[1] = f.y;
  f = __half22float2(*(const __half2*)&q.y); p[2] = f.x; p[3] = f.y;
  f = __half22float2(*(const __half2*)&q.z); p[4] = f.x; p[5] = f.y;
  f = __half22float2(*(const __half2*)&q.w); p[6] = f.x; p[7] = f.y;
}

// ---------------------------------------------------------------------------
// Gather over the 16B-row fp16 table. All index loads issue first
// (non-temporal), then ALL row loads (one big independent in-flight group —
// the latency-hiding lever proven in R5), then compute. Tails branch-free.
// Finalize fused via done-counter.
// ---------------------------------------------------------------------------
__global__ __launch_bounds__(256) void gather_energy16(
    const int4* __restrict__ T,
    const int* __restrict__ s1, int nP,
    const int* __restrict__ s2, int nT,
    double* __restrict__ acc, unsigned int* __restrict__ cnt,
    int pairBlocks, int totalBlocks,
    float* __restrict__ out, double cst) {
  __shared__ float smem[4];
  float local = 0.f;

  if ((int)blockIdx.x < pairBlocks) {
    const unsigned long long* __restrict__ s1q = (const unsigned long long*)s1;
    int base = blockIdx.x * (256 * BP) + threadIdx.x;
    int   va[BP], vb[BP];
    float w[BP];
#pragma unroll
    for (int u = 0; u < BP; ++u) {
      int i  = base + u * 256;
      int ii = min(i, nP - 1);
      w[u]   = (i < nP) ? 1.0f : 0.0f;
      unsigned long long q = __builtin_nontemporal_load(s1q + ii);
      va[u] = (int)(unsigned int)q;
      vb[u] = (int)(q >> 32);
    }
    int4 qa[BP], qb[BP];
#pragma unroll
    for (int u = 0; u < BP; ++u) { qa[u] = T[va[u]]; qb[u] = T[vb[u]]; }
#pragma unroll
    for (int u = 0; u < BP; ++u) {
      float pa[N_L], pb[N_L];
      unpack8(qa[u], pa);
      unpack8(qb[u], pb);
      float d = 0.f;
#pragma unroll
      for (int t = 0; t < N_L; ++t) d += pa[t] * pb[t];
      local -= w[u] * d;
    }
  } else {
    int base = (blockIdx.x - pairBlocks) * (256 * BT) + threadIdx.x;
    int   v0[BT], v1[BT], v2[BT];
    float w[BT];
#pragma unroll
    for (int u = 0; u < BT; ++u) {
      int i  = base + u * 256;
      int ii = min(i, nT - 1);
      w[u]   = (i < nT) ? 1.0f : 0.0f;
      v0[u] = __builtin_nontemporal_load(s2 + 3 * ii + 0);
      v1[u] = __builtin_nontemporal_load(s2 + 3 * ii + 1);
      v2[u] = __builtin_nontemporal_load(s2 + 3 * ii + 2);
    }
    int4 qa[BT], qb[BT], qc[BT];
#pragma unroll
    for (int u = 0; u < BT; ++u) { qa[u] = T[v0[u]]; qb[u] = T[v1[u]]; qc[u] = T[v2[u]]; }
#pragma unroll
    for (int u = 0; u < BT; ++u) {
      float pa[N_L], pb[N_L], pc[N_L];
      unpack8(qa[u], pa);
      unpack8(qb[u], pb);
      unpack8(qc[u], pc);
      float d01 = 0.f, d02 = 0.f, d12 = 0.f, t3 = 0.f;
#pragma unroll
      for (int t = 0; t < N_L; ++t) {
        d01 += pa[t] * pb[t];
        d02 += pa[t] * pc[t];
        d12 += pb[t] * pc[t];
        t3  += pa[t] * pb[t] * pc[t];
      }
      local += w[u] * (-4.0f * (d01 + d02 + d12) + (16.0f / 3.0f) * t3);
    }
  }

  float bsum = block_reduce_sum(local, smem);
  if (threadIdx.x == 0) {
    atomicAdd(acc, (double)bsum);
    __threadfence();
    unsigned int done = atomicAdd(cnt, 1u);
    if (done == (unsigned int)(totalBlocks - 1)) {
      double total = atomicAdd(acc, 0.0);  // coherent read
      out[0] = (float)(cst + total);
    }
  }
}

// ---------------------------------------------------------------------------
// ws-too-small fallback: fully fused f32 kernel (proven R1), no table.
// ---------------------------------------------------------------------------
__device__ __forceinline__ const float* row_ptr(
    int v, bool ar, const int* __restrict__ tab, int nF,
    const float* __restrict__ tr, const float* __restrict__ fx) {
  if (ar) {
    return (v < nF) ? (fx + (size_t)v * N_L) : (tr + (size_t)(v - nF) * N_L);
  }
  int lo = 0, hi = nF;
  while (lo < hi) {
    int mid = (lo + hi) >> 1;
    if (tab[mid] < v) lo = mid + 1; else hi = mid;
  }
  return (lo < nF && tab[lo] == v) ? (fx + (size_t)lo * N_L)
                                   : (tr + (size_t)(v - lo) * N_L);
}

__device__ __forceinline__ void softmax8(float p[N_L]) {
  float m = p[0];
#pragma unroll
  for (int i = 1; i < N_L; ++i) m = fmaxf(m, p[i]);
  float s = 0.f;
#pragma unroll
  for (int i = 0; i < N_L; ++i) { p[i] = __expf(p[i] - m); s += p[i]; }
  float r = 1.0f / s;
#pragma unroll
  for (int i = 0; i < N_L; ++i) p[i] *= r;
}

__global__ __launch_bounds__(256) void fused_energy(
    const float* __restrict__ tr, const float* __restrict__ fx,
    const int* __restrict__ fidx, int nF,
    const int* __restrict__ s1, int nP,
    const int* __restrict__ s2, int nT,
    double* __restrict__ acc, unsigned int* __restrict__ cnt,
    int pairBlocks, int totalBlocks,
    float* __restrict__ out, double cst) {
  __shared__ float smem[4];
  __shared__ int sf[1024];

  const bool ar = (nF == 0) || (fidx[0] == 0 && fidx[nF - 1] == nF - 1);
  const bool useLds = (!ar && nF <= 1024);
  if (useLds) {
    for (int j = threadIdx.x; j < nF; j += 256) sf[j] = fidx[j];
    __syncthreads();
  }
  const int* __restrict__ tab = useLds ? sf : fidx;

  float local = 0.f;

  if ((int)blockIdx.x < pairBlocks) {
    const unsigned long long* __restrict__ s1q = (const unsigned long long*)s1;
    int base = blockIdx.x * (256 * 4) + threadIdx.x;
    int   va[4], vb[4];
    float w[4];
#pragma unroll
    for (int u = 0; u < 4; ++u) {
      int i  = base + u * 256;
      int ii = min(i, nP - 1);
      w[u]   = (i < nP) ? 1.0f : 0.0f;
      unsigned long long q = __builtin_nontemporal_load(s1q + ii);
      va[u] = (int)(unsigned int)q;
      vb[u] = (int)(q >> 32);
    }
    float4 a0[4], a1[4], b0[4], b1[4];
#pragma unroll
    for (int u = 0; u < 4; ++u) {
      const float4* A = (const float4*)row_ptr(va[u], ar, tab, nF, tr, fx);
      const float4* B = (const float4*)row_ptr(vb[u], ar, tab, nF, tr, fx);
      a0[u] = A[0]; a1[u] = A[1];
      b0[u] = B[0]; b1[u] = B[1];
    }
#pragma unroll
    for (int u = 0; u < 4; ++u) {
      float pa[8] = {a0[u].x, a0[u].y, a0[u].z, a0[u].w, a1[u].x, a1[u].y, a1[u].z, a1[u].w};
      float pb[8] = {b0[u].x, b0[u].y, b0[u].z, b0[u].w, b1[u].x, b1[u].y, b1[u].z, b1[u].w};
      softmax8(pa);
      softmax8(pb);
      float d = 0.f;
#pragma unroll
      for (int t = 0; t < N_L; ++t) d += pa[t] * pb[t];
      local -= w[u] * d;
    }
  } else {
    int base = (blockIdx.x - pairBlocks) * (256 * 2) + threadIdx.x;
    int   v0[2], v1[2], v2[2];
    float w[2];
#pragma unroll
    for (int u = 0; u < 2; ++u) {
      int i  = base + u * 256;
      int ii = min(i, nT - 1);
      w[u]   = (i < nT) ? 1.0f : 0.0f;
      v0[u] = __builtin_nontemporal_load(s2 + 3 * ii + 0);
      v1[u] = __builtin_nontemporal_load(s2 + 3 * ii + 1);
      v2[u] = __builtin_nontemporal_load(s2 + 3 * ii + 2);
    }
    float4 a0[2], a1[2], b0[2], b1[2], c0[2], c1[2];
#pragma unroll
    for (int u = 0; u < 2; ++u) {
      const float4* A = (const float4*)row_ptr(v0[u], ar, tab, nF, tr, fx);
      const float4* B = (const float4*)row_ptr(v1[u], ar, tab, nF, tr, fx);
      const float4* C = (const float4*)row_ptr(v2[u], ar, tab, nF, tr, fx);
      a0[u] = A[0]; a1[u] = A[1];
      b0[u] = B[0]; b1[u] = B[1];
      c0[u] = C[0]; c1[u] = C[1];
    }
#pragma unroll
    for (int u = 0; u < 2; ++u) {
      float pa[8] = {a0[u].x, a0[u].y, a0[u].z, a0[u].w, a1[u].x, a1[u].y, a1[u].z, a1[u].w};
      float pb[8] = {b0[u].x, b0[u].y, b0[u].z, b0[u].w, b1[u].x, b1[u].y, b1[u].z, b1[u].w};
      float pc[8] = {c0[u].x, c0[u].y, c0[u].z, c0[u].w, c1[u].x, c1[u].y, c1[u].z, c1[u].w};
      softmax8(pa);
      softmax8(pb);
      softmax8(pc);
      float d01 = 0.f, d02 = 0.f, d12 = 0.f, t3 = 0.f;
#pragma unroll
      for (int t = 0; t < N_L; ++t) {
        d01 += pa[t] * pb[t];
        d02 += pa[t] * pc[t];
        d12 += pb[t] * pc[t];
        t3  += pa[t] * pb[t] * pc[t];
      }
      local += w[u] * (-4.0f * (d01 + d02 + d12) + (16.0f / 3.0f) * t3);
    }
  }

  float bsum = block_reduce_sum(local, smem);
  if (threadIdx.x == 0) {
    atomicAdd(acc, (double)bsum);
    __threadfence();
    unsigned int done = atomicAdd(cnt, 1u);
    if (done == (unsigned int)(totalBlocks - 1)) {
      double total = atomicAdd(acc, 0.0);
      out[0] = (float)(cst + total);
    }
  }
}

extern "C" void kernel_launch(void* const* d_in, const int* in_sizes, int n_in,
                              void* d_out, int out_size, void* d_ws, size_t ws_size,
                              hipStream_t stream) {
  const float* tr   = (const float*)d_in[0];  // (N_V-N_FIXED, 8) f32
  const float* fx   = (const float*)d_in[1];  // (N_FIXED, 8) f32
  const int*   fidx = (const int*)d_in[2];    // (N_FIXED,) i32 (sorted)
  const int*   s1   = (const int*)d_in[3];    // (nP, 2) i32
  const int*   s2   = (const int*)d_in[4];    // (nT, 3) i32

  int nF = in_sizes[2];
  int nP = in_sizes[3] / 2;
  int nT = in_sizes[4] / 3;
  int nV = (in_sizes[0] + in_sizes[1]) / N_L;

  double*       acc = (double*)d_ws;                      // @0, 8B
  unsigned int* cnt = (unsigned int*)((char*)d_ws + 16);  // @16, 4B
  int4*         T   = (int4*)((char*)d_ws + 256);         // nV x 16B fp16 rows
  float*        out = (float*)d_out;

  double cst = 2.0 * (double)nP + 8.0 * (double)nT;

  size_t need16 = 256 + (size_t)nV * 16;
  if (ws_size >= need16) {
    int pairBlocks  = (nP + 256 * BP - 1) / (256 * BP);
    int triBlocks   = (nT + 256 * BT - 1) / (256 * BT);
    int totalBlocks = pairBlocks + triBlocks;
    materialize_P16<<<(nV + 255) / 256, 256, 0, stream>>>(tr, fx, fidx, nF, nV, T, acc, cnt);
    gather_energy16<<<totalBlocks, 256, 0, stream>>>(
        T, s1, nP, s2, nT, acc, cnt, pairBlocks, totalBlocks, out, cst);
  } else {
    int pairBlocks  = (nP + 256 * 4 - 1) / (256 * 4);
    int triBlocks   = (nT + 256 * 2 - 1) / (256 * 2);
    int totalBlocks = pairBlocks + triBlocks;
    hipMemsetAsync(d_ws, 0, 32, stream);
    fused_energy<<<totalBlocks, 256, 0, stream>>>(
        tr, fx, fidx, nF, s1, nP, s2, nT, acc, cnt,
        pairBlocks, totalBlocks, out, cst);
  }
}

// Round 8
// 92.146 us; speedup vs baseline: 2.3848x; 1.0633x over previous
//
#include <hip/hip_runtime.h>
#include <hip/hip_fp16.h>

#define N_L 8
#define BP 25  // pairs per thread   (125 blocks: one balanced round on 256 CUs)
#define BT 13  // triples per thread (121 blocks)

// ---------------------------------------------------------------------------
// Block (256 threads = 4 waves) sum reduction; result valid on thread 0.
// ---------------------------------------------------------------------------
__device__ __forceinline__ float block_reduce_sum(float v, float* smem) {
#pragma unroll
  for (int off = 32; off > 0; off >>= 1) v += __shfl_down(v, off, 64);
  int lane = threadIdx.x & 63;
  int wid  = threadIdx.x >> 6;
  if (lane == 0) smem[wid] = v;
  __syncthreads();
  if (threadIdx.x < 4) {
    v = smem[threadIdx.x];
    v += __shfl_down(v, 2, 64);
    v += __shfl_down(v, 1, 64);
  }
  return v;
}

// ---------------------------------------------------------------------------
// Materialize fp16 softmax table: nV x 8 half = 16B rows (one dwordx4 per
// random row-gather). Softmax in f32, round-to-nearest fp16 at store.
// Also zero-inits acc + done-counter.
// Fast path: fidx == arange(nF); fallback binary search (LDS-staged).
// ---------------------------------------------------------------------------
__global__ __launch_bounds__(256) void materialize_P16(
    const float* __restrict__ tr, const float* __restrict__ fx,
    const int* __restrict__ fidx, int nF, int nV,
    int4* __restrict__ T, double* __restrict__ acc,
    unsigned int* __restrict__ cnt) {
  __shared__ int sf[1024];
  const bool ar = (nF == 0) || (fidx[0] == 0 && fidx[nF - 1] == nF - 1);
  const bool useLds = (!ar && nF <= 1024);
  if (useLds) {
    for (int j = threadIdx.x; j < nF; j += 256) sf[j] = fidx[j];
    __syncthreads();
  }
  int v = blockIdx.x * 256 + threadIdx.x;
  if (v == 0) { acc[0] = 0.0; cnt[0] = 0u; }
  if (v >= nV) return;

  const float* src;
  if (ar) {
    src = (v < nF) ? (fx + (size_t)v * N_L) : (tr + (size_t)(v - nF) * N_L);
  } else {
    const int* __restrict__ tab = useLds ? sf : fidx;
    int lo = 0, hi = nF;
    while (lo < hi) {
      int mid = (lo + hi) >> 1;
      if (tab[mid] < v) lo = mid + 1; else hi = mid;
    }
    src = (lo < nF && tab[lo] == v) ? (fx + (size_t)lo * N_L)
                                    : (tr + (size_t)(v - lo) * N_L);
  }
  float p[N_L];
  float4 a = *(const float4*)src;
  float4 b = *(const float4*)(src + 4);
  p[0] = a.x; p[1] = a.y; p[2] = a.z; p[3] = a.w;
  p[4] = b.x; p[5] = b.y; p[6] = b.z; p[7] = b.w;
  float m = p[0];
#pragma unroll
  for (int i = 1; i < N_L; ++i) m = fmaxf(m, p[i]);
  float s = 0.f;
#pragma unroll
  for (int i = 0; i < N_L; ++i) { p[i] = __expf(p[i] - m); s += p[i]; }
  float r = 1.0f / s;
  __half2 h0 = __floats2half2_rn(p[0] * r, p[1] * r);
  __half2 h1 = __floats2half2_rn(p[2] * r, p[3] * r);
  __half2 h2 = __floats2half2_rn(p[4] * r, p[5] * r);
  __half2 h3 = __floats2half2_rn(p[6] * r, p[7] * r);
  int4 o;
  o.x = *(const int*)&h0;
  o.y = *(const int*)&h1;
  o.z = *(const int*)&h2;
  o.w = *(const int*)&h3;
  T[v] = o;
}

__device__ __forceinline__ void unpack8(int4 q, float p[N_L]) {
  float2 f;
  f = __half22float2(*(const __half2*)&q.x); p[0] = f.x; p[1] = f.y;
  f = __half22float2(*(const __half2*)&q.y); p[2] = f.x; p[3] = f.y;
  f = __half22float2(*(const __half2*)&q.z); p[4] = f.x; p[5] = f.y;
  f = __half22float2(*(const __half2*)&q.w); p[6] = f.x; p[7] = f.y;
}

// ---------------------------------------------------------------------------
// Gather over the 16B-row fp16 table. All index loads issue first
// (non-temporal), then ALL row loads (one big independent in-flight group —
// the latency-hiding lever proven in R5/R7), then compute. Grid sized to ONE
// balanced round (246 blocks, 1 wave/SIMD at high VGPR — intentional).
// Tails branch-free. Finalize fused via done-counter.
// ---------------------------------------------------------------------------
__global__ __launch_bounds__(256, 1) void gather_energy16(
    const int4* __restrict__ T,
    const int* __restrict__ s1, int nP,
    const int* __restrict__ s2, int nT,
    double* __restrict__ acc, unsigned int* __restrict__ cnt,
    int pairBlocks, int totalBlocks,
    float* __restrict__ out, double cst) {
  __shared__ float smem[4];
  float local = 0.f;

  if ((int)blockIdx.x < pairBlocks) {
    const unsigned long long* __restrict__ s1q = (const unsigned long long*)s1;
    int base = blockIdx.x * (256 * BP) + threadIdx.x;
    int   va[BP], vb[BP];
    float w[BP];
#pragma unroll
    for (int u = 0; u < BP; ++u) {
      int i  = base + u * 256;
      int ii = min(i, nP - 1);
      w[u]   = (i < nP) ? 1.0f : 0.0f;
      unsigned long long q = __builtin_nontemporal_load(s1q + ii);
      va[u] = (int)(unsigned int)q;
      vb[u] = (int)(q >> 32);
    }
    int4 qa[BP], qb[BP];
#pragma unroll
    for (int u = 0; u < BP; ++u) { qa[u] = T[va[u]]; qb[u] = T[vb[u]]; }
#pragma unroll
    for (int u = 0; u < BP; ++u) {
      float pa[N_L], pb[N_L];
      unpack8(qa[u], pa);
      unpack8(qb[u], pb);
      float d = 0.f;
#pragma unroll
      for (int t = 0; t < N_L; ++t) d += pa[t] * pb[t];
      local -= w[u] * d;
    }
  } else {
    int base = (blockIdx.x - pairBlocks) * (256 * BT) + threadIdx.x;
    int   v0[BT], v1[BT], v2[BT];
    float w[BT];
#pragma unroll
    for (int u = 0; u < BT; ++u) {
      int i  = base + u * 256;
      int ii = min(i, nT - 1);
      w[u]   = (i < nT) ? 1.0f : 0.0f;
      v0[u] = __builtin_nontemporal_load(s2 + 3 * ii + 0);
      v1[u] = __builtin_nontemporal_load(s2 + 3 * ii + 1);
      v2[u] = __builtin_nontemporal_load(s2 + 3 * ii + 2);
    }
    int4 qa[BT], qb[BT], qc[BT];
#pragma unroll
    for (int u = 0; u < BT; ++u) { qa[u] = T[v0[u]]; qb[u] = T[v1[u]]; qc[u] = T[v2[u]]; }
#pragma unroll
    for (int u = 0; u < BT; ++u) {
      float pa[N_L], pb[N_L], pc[N_L];
      unpack8(qa[u], pa);
      unpack8(qb[u], pb);
      unpack8(qc[u], pc);
      float d01 = 0.f, d02 = 0.f, d12 = 0.f, t3 = 0.f;
#pragma unroll
      for (int t = 0; t < N_L; ++t) {
        d01 += pa[t] * pb[t];
        d02 += pa[t] * pc[t];
        d12 += pb[t] * pc[t];
        t3  += pa[t] * pb[t] * pc[t];
      }
      local += w[u] * (-4.0f * (d01 + d02 + d12) + (16.0f / 3.0f) * t3);
    }
  }

  float bsum = block_reduce_sum(local, smem);
  if (threadIdx.x == 0) {
    atomicAdd(acc, (double)bsum);
    __threadfence();
    unsigned int done = atomicAdd(cnt, 1u);
    if (done == (unsigned int)(totalBlocks - 1)) {
      double total = atomicAdd(acc, 0.0);  // coherent read
      out[0] = (float)(cst + total);
    }
  }
}

// ---------------------------------------------------------------------------
// ws-too-small fallback: fully fused f32 kernel (proven R1), no table.
// ---------------------------------------------------------------------------
__device__ __forceinline__ const float* row_ptr(
    int v, bool ar, const int* __restrict__ tab, int nF,
    const float* __restrict__ tr, const float* __restrict__ fx) {
  if (ar) {
    return (v < nF) ? (fx + (size_t)v * N_L) : (tr + (size_t)(v - nF) * N_L);
  }
  int lo = 0, hi = nF;
  while (lo < hi) {
    int mid = (lo + hi) >> 1;
    if (tab[mid] < v) lo = mid + 1; else hi = mid;
  }
  return (lo < nF && tab[lo] == v) ? (fx + (size_t)lo * N_L)
                                   : (tr + (size_t)(v - lo) * N_L);
}

__device__ __forceinline__ void softmax8(float p[N_L]) {
  float m = p[0];
#pragma unroll
  for (int i = 1; i < N_L; ++i) m = fmaxf(m, p[i]);
  float s = 0.f;
#pragma unroll
  for (int i = 0; i < N_L; ++i) { p[i] = __expf(p[i] - m); s += p[i]; }
  float r = 1.0f / s;
#pragma unroll
  for (int i = 0; i < N_L; ++i) p[i] *= r;
}

__global__ __launch_bounds__(256) void fused_energy(
    const float* __restrict__ tr, const float* __restrict__ fx,
    const int* __restrict__ fidx, int nF,
    const int* __restrict__ s1, int nP,
    const int* __restrict__ s2, int nT,
    double* __restrict__ acc, unsigned int* __restrict__ cnt,
    int pairBlocks, int totalBlocks,
    float* __restrict__ out, double cst) {
  __shared__ float smem[4];
  __shared__ int sf[1024];

  const bool ar = (nF == 0) || (fidx[0] == 0 && fidx[nF - 1] == nF - 1);
  const bool useLds = (!ar && nF <= 1024);
  if (useLds) {
    for (int j = threadIdx.x; j < nF; j += 256) sf[j] = fidx[j];
    __syncthreads();
  }
  const int* __restrict__ tab = useLds ? sf : fidx;

  float local = 0.f;

  if ((int)blockIdx.x < pairBlocks) {
    const unsigned long long* __restrict__ s1q = (const unsigned long long*)s1;
    int base = blockIdx.x * (256 * 4) + threadIdx.x;
    int   va[4], vb[4];
    float w[4];
#pragma unroll
    for (int u = 0; u < 4; ++u) {
      int i  = base + u * 256;
      int ii = min(i, nP - 1);
      w[u]   = (i < nP) ? 1.0f : 0.0f;
      unsigned long long q = __builtin_nontemporal_load(s1q + ii);
      va[u] = (int)(unsigned int)q;
      vb[u] = (int)(q >> 32);
    }
    float4 a0[4], a1[4], b0[4], b1[4];
#pragma unroll
    for (int u = 0; u < 4; ++u) {
      const float4* A = (const float4*)row_ptr(va[u], ar, tab, nF, tr, fx);
      const float4* B = (const float4*)row_ptr(vb[u], ar, tab, nF, tr, fx);
      a0[u] = A[0]; a1[u] = A[1];
      b0[u] = B[0]; b1[u] = B[1];
    }
#pragma unroll
    for (int u = 0; u < 4; ++u) {
      float pa[8] = {a0[u].x, a0[u].y, a0[u].z, a0[u].w, a1[u].x, a1[u].y, a1[u].z, a1[u].w};
      float pb[8] = {b0[u].x, b0[u].y, b0[u].z, b0[u].w, b1[u].x, b1[u].y, b1[u].z, b1[u].w};
      softmax8(pa);
      softmax8(pb);
      float d = 0.f;
#pragma unroll
      for (int t = 0; t < N_L; ++t) d += pa[t] * pb[t];
      local -= w[u] * d;
    }
  } else {
    int base = (blockIdx.x - pairBlocks) * (256 * 2) + threadIdx.x;
    int   v0[2], v1[2], v2[2];
    float w[2];
#pragma unroll
    for (int u = 0; u < 2; ++u) {
      int i  = base + u * 256;
      int ii = min(i, nT - 1);
      w[u]   = (i < nT) ? 1.0f : 0.0f;
      v0[u] = __builtin_nontemporal_load(s2 + 3 * ii + 0);
      v1[u] = __builtin_nontemporal_load(s2 + 3 * ii + 1);
      v2[u] = __builtin_nontemporal_load(s2 + 3 * ii + 2);
    }
    float4 a0[2], a1[2], b0[2], b1[2], c0[2], c1[2];
#pragma unroll
    for (int u = 0; u < 2; ++u) {
      const float4* A = (const float4*)row_ptr(v0[u], ar, tab, nF, tr, fx);
      const float4* B = (const float4*)row_ptr(v1[u], ar, tab, nF, tr, fx);
      const float4* C = (const float4*)row_ptr(v2[u], ar, tab, nF, tr, fx);
      a0[u] = A[0]; a1[u] = A[1];
      b0[u] = B[0]; b1[u] = B[1];
      c0[u] = C[0]; c1[u] = C[1];
    }
#pragma unroll
    for (int u = 0; u < 2; ++u) {
      float pa[8] = {a0[u].x, a0[u].y, a0[u].z, a0[u].w, a1[u].x, a1[u].y, a1[u].z, a1[u].w};
      float pb[8] = {b0[u].x, b0[u].y, b0[u].z, b0[u].w, b1[u].x, b1[u].y, b1[u].z, b1[u].w};
      float pc[8] = {c0[u].x, c0[u].y, c0[u].z, c0[u].w, c1[u].x, c1[u].y, c1[u].z, c1[u].w};
      softmax8(pa);
      softmax8(pb);
      softmax8(pc);
      float d01 = 0.f, d02 = 0.f, d12 = 0.f, t3 = 0.f;
#pragma unroll
      for (int t = 0; t < N_L; ++t) {
        d01 += pa[t] * pb[t];
        d02 += pa[t] * pc[t];
        d12 += pb[t] * pc[t];
        t3  += pa[t] * pb[t] * pc[t];
      }
      local += w[u] * (-4.0f * (d01 + d02 + d12) + (16.0f / 3.0f) * t3);
    }
  }

  float bsum = block_reduce_sum(local, smem);
  if (threadIdx.x == 0) {
    atomicAdd(acc, (double)bsum);
    __threadfence();
    unsigned int done = atomicAdd(cnt, 1u);
    if (done == (unsigned int)(totalBlocks - 1)) {
      double total = atomicAdd(acc, 0.0);
      out[0] = (float)(cst + total);
    }
  }
}

extern "C" void kernel_launch(void* const* d_in, const int* in_sizes, int n_in,
                              void* d_out, int out_size, void* d_ws, size_t ws_size,
                              hipStream_t stream) {
  const float* tr   = (const float*)d_in[0];  // (N_V-N_FIXED, 8) f32
  const float* fx   = (const float*)d_in[1];  // (N_FIXED, 8) f32
  const int*   fidx = (const int*)d_in[2];    // (N_FIXED,) i32 (sorted)
  const int*   s1   = (const int*)d_in[3];    // (nP, 2) i32
  const int*   s2   = (const int*)d_in[4];    // (nT, 3) i32

  int nF = in_sizes[2];
  int nP = in_sizes[3] / 2;
  int nT = in_sizes[4] / 3;
  int nV = (in_sizes[0] + in_sizes[1]) / N_L;

  double*       acc = (double*)d_ws;                      // @0, 8B
  unsigned int* cnt = (unsigned int*)((char*)d_ws + 16);  // @16, 4B
  int4*         T   = (int4*)((char*)d_ws + 256);         // nV x 16B fp16 rows
  float*        out = (float*)d_out;

  double cst = 2.0 * (double)nP + 8.0 * (double)nT;

  size_t need16 = 256 + (size_t)nV * 16;
  if (ws_size >= need16) {
    int pairBlocks  = (nP + 256 * BP - 1) / (256 * BP);
    int triBlocks   = (nT + 256 * BT - 1) / (256 * BT);
    int totalBlocks = pairBlocks + triBlocks;
    materialize_P16<<<(nV + 255) / 256, 256, 0, stream>>>(tr, fx, fidx, nF, nV, T, acc, cnt);
    gather_energy16<<<totalBlocks, 256, 0, stream>>>(
        T, s1, nP, s2, nT, acc, cnt, pairBlocks, totalBlocks, out, cst);
  } else {
    int pairBlocks  = (nP + 256 * 4 - 1) / (256 * 4);
    int triBlocks   = (nT + 256 * 2 - 1) / (256 * 2);
    int totalBlocks = pairBlocks + triBlocks;
    hipMemsetAsync(d_ws, 0, 32, stream);
    fused_energy<<<totalBlocks, 256, 0, stream>>>(
        tr, fx, fidx, nF, s1, nP, s2, nT, acc, cnt,
        pairBlocks, totalBlocks, out, cst);
  }
}